// Round 1
// baseline (60.336 us; speedup 1.0000x reference)
//
#include <hip/hip_runtime.h>
#include <hip/hip_bf16.h>

// out[i,d] = mu[i,d] + sigma[i,d] * scale(i) * e[i,d]
// scale(i) = sqrt(EPS) if parent[i]==-1 else 1.0
// Derivation: L in the reference is diagonal (L=L[p_idx]*gamma starts from a
// zero tensor), diag = sqrt(clip(1 - root, eps)) -> sqrt(eps) for roots, 1 else.
// gamma is dead. D=32 -> 8 float4 per row.

#define SQRT_EPS 0.03162277660168379f

__global__ __launch_bounds__(256) void vae_vi_kernel(
    const float4* __restrict__ mu,
    const float4* __restrict__ sigma,
    const float4* __restrict__ e,
    const int* __restrict__ parent,
    float4* __restrict__ out,
    int n4)
{
    int idx = blockIdx.x * blockDim.x + threadIdx.x;
    if (idx >= n4) return;
    int row = idx >> 3;  // D/4 = 8 float4 per row
    float scale = (parent[row] == -1) ? SQRT_EPS : 1.0f;
    float4 m = mu[idx];
    float4 s = sigma[idx];
    float4 ev = e[idx];
    float4 o;
    o.x = fmaf(s.x * scale, ev.x, m.x);
    o.y = fmaf(s.y * scale, ev.y, m.y);
    o.z = fmaf(s.z * scale, ev.z, m.z);
    o.w = fmaf(s.w * scale, ev.w, m.w);
    out[idx] = o;
}

extern "C" void kernel_launch(void* const* d_in, const int* in_sizes, int n_in,
                              void* d_out, int out_size, void* d_ws, size_t ws_size,
                              hipStream_t stream) {
    const float4* mu    = (const float4*)d_in[0];
    const float4* sigma = (const float4*)d_in[1];
    // d_in[2] = gamma, unused (dead in the reference computation)
    const float4* e     = (const float4*)d_in[3];
    const int* parent   = (const int*)d_in[4];
    float4* out = (float4*)d_out;

    int n4 = out_size / 4;  // 65536/4 = 16384
    int block = 256;
    int grid = (n4 + block - 1) / block;
    vae_vi_kernel<<<grid, block, 0, stream>>>(mu, sigma, e, parent, out, n4);
}